// Round 1
// baseline (980.774 us; speedup 1.0000x reference)
//
#include <hip/hip_runtime.h>

// Sizes for this problem instance
#define DD   160      // D = T
#define KKE  589      // number of estimator columns
#define RR   8        // rank
#define NNX  32768    // N = C*H*W
#define NB   8        // batch (B*S)
#define EPSN 1e-6f

// ---------------------------------------------------------------------------
// Build E [D,K] and ET [K,D]. grid 160 blocks (one per t), 256 threads.
__global__ __launch_bounds__(256) void k_build(float* __restrict__ E, float* __restrict__ ET) {
    const int t = blockIdx.x;
    for (int j = threadIdx.x; j < KKE; j += 256) {
        float val;
        if (j == 588) {
            val = 1.f;
        } else {
            int n; float s2x4;
            if (j < 160)      { n = j;           s2x4 = 144.f;  }   // sig 6
            else if (j < 320) { n = j - 160;     s2x4 = 256.f;  }   // sig 8
            else if (j < 400) { n = 2*(j - 320); s2x4 = 576.f;  }   // sig 12
            else if (j < 480) { n = 2*(j - 400); s2x4 = 900.f;  }   // sig 15
            else if (j < 534) { n = 3*(j - 480); s2x4 = 1296.f; }   // sig 18
            else              { n = 3*(j - 534); s2x4 = 2304.f; }   // sig 24
            float d = (float)(t - n);
            val = expf(-(d * d) / s2x4);
        }
        E[t*KKE + j]  = val;
        ET[j*DD + t]  = val;
    }
}

// ---------------------------------------------------------------------------
// Eb[b,d,r] = sum_k E[d,k]*bases[b,k,r].  Optionally L2-normalize bases first
// (init). Also zeroes xc and ctc accumulators (handles 0xAA ws poison).
// grid 64 = (b,r) blocks, 256 threads.
template <bool NORM>
__global__ __launch_bounds__(256) void k_eb(const float* __restrict__ ET,
                                            const float* __restrict__ bsrc,
                                            float* __restrict__ bnorm_out,
                                            float* __restrict__ Eb_out,
                                            float* __restrict__ xc,
                                            float* __restrict__ ctc) {
    __shared__ float bcol[KKE];
    __shared__ float etch[64 * DD];   // 40 KB chunk of ET
    __shared__ float red[4];
    const int tid = threadIdx.x;
    const int b = blockIdx.x >> 3;
    const int r = blockIdx.x & 7;

    const int k0 = tid, k1 = tid + 256, k2 = tid + 512;
    float v0 = bsrc[(b*KKE + k0)*RR + r];
    float v1 = bsrc[(b*KKE + k1)*RR + r];
    float v2 = (k2 < KKE) ? bsrc[(b*KKE + k2)*RR + r] : 0.f;

    if (NORM) {
        float ss = v0*v0 + v1*v1 + v2*v2;
        #pragma unroll
        for (int off = 32; off; off >>= 1) ss += __shfl_xor(ss, off);
        if ((tid & 63) == 0) red[tid >> 6] = ss;
        __syncthreads();
        float tot = red[0] + red[1] + red[2] + red[3];
        float scale = 1.f / fmaxf(sqrtf(tot), 1e-12f);
        v0 *= scale; v1 *= scale; v2 *= scale;
        bnorm_out[(b*KKE + k0)*RR + r] = v0;
        bnorm_out[(b*KKE + k1)*RR + r] = v1;
        if (k2 < KKE) bnorm_out[(b*KKE + k2)*RR + r] = v2;
    }
    bcol[k0] = v0; bcol[k1] = v1; if (k2 < KKE) bcol[k2] = v2;
    __syncthreads();

    float acc = 0.f;
    for (int c0 = 0; c0 < KKE; c0 += 64) {
        const int kcn = (KKE - c0 < 64) ? (KKE - c0) : 64;
        const int nf4 = kcn * (DD/4);
        for (int i4 = tid; i4 < nf4; i4 += 256)
            *(float4*)&etch[i4*4] = *(const float4*)&ET[c0*DD + i4*4];
        __syncthreads();
        if (tid < DD) {
            #pragma unroll 4
            for (int kk = 0; kk < kcn; ++kk)
                acc += etch[kk*DD + tid] * bcol[c0 + kk];
        }
        __syncthreads();
    }
    if (tid < DD) {
        Eb_out[b*DD*RR + tid*RR + r] = acc;
        xc[b*DD*RR + tid*RR + r] = 0.f;       // reset accumulator
    }
    if (tid < 8) ctc[b*64 + tid*8 + r] = 0.f; // reset accumulator
}

// ---------------------------------------------------------------------------
// Fused coef-update step.  grid (128, 8), 256 threads, 4 subtiles of 64 cols.
// FIRST: coef_old = softmax(num_c) (init fused with step 1).
// Writes coef_new to global; accumulates xc += x*coef_new, ctc += c^T c.
template <bool FIRST>
__global__ __launch_bounds__(256) void k_step(const float* __restrict__ x,
                                              const float* __restrict__ Eb_g,
                                              float* __restrict__ coef,
                                              float* __restrict__ xc,
                                              float* __restrict__ ctc) {
    __shared__ float eb[DD*RR];        // [d][r]
    __shared__ float ebteb[64];        // [r][s]
    __shared__ float xt[64*161];       // x tile transposed [n][d], pad 161
    __shared__ float pn[1536];         // phase1 partials [q-1][r][c]; aliased: cnew [n][r]

    const int tid = threadIdx.x;
    const int b = blockIdx.y;
    const int base_n = blockIdx.x * 256;

    for (int i = tid; i < DD*RR; i += 256) eb[i] = Eb_g[b*DD*RR + i];
    __syncthreads();
    if (tid < 64) {
        const int r = tid >> 3, s = tid & 7;
        float a = 0.f;
        #pragma unroll 4
        for (int d = 0; d < DD; ++d) a += eb[d*RR + r] * eb[d*RR + s];
        ebteb[tid] = a;
    }
    __syncthreads();

    float xcp[8] = {0,0,0,0,0,0,0,0};   // threads < 160: xc partial for d=tid
    float ctcp = 0.f;                    // threads >= 192: ctc partial (r,s)

    const int q = tid >> 6;   // d-quarter
    const int c = tid & 63;   // column within subtile

    for (int st = 0; st < 4; ++st) {
        const int n0 = base_n + st*64;
        // ---- stage x tile (transposed scatter into LDS) ----
        #pragma unroll
        for (int it = 0; it < 10; ++it) {
            const int idx = tid + it*256;      // 0..2559 float4s
            const int row = idx >> 4;          // d
            const int c4  = (idx & 15) << 2;   // n chunk
            const float4 v = *(const float4*)&x[(b*DD + row)*NNX + n0 + c4];
            xt[(c4+0)*161 + row] = v.x;
            xt[(c4+1)*161 + row] = v.y;
            xt[(c4+2)*161 + row] = v.z;
            xt[(c4+3)*161 + row] = v.w;
        }
        __syncthreads();
        // ---- phase 1: num_c partials ----
        float nc[8] = {0,0,0,0,0,0,0,0};
        {
            const int dbase = q*40;
            #pragma unroll 4
            for (int dd = 0; dd < 40; ++dd) {
                const int d = dbase + dd;
                const float xv = xt[c*161 + d];
                const float4 e0 = *(const float4*)&eb[d*RR];
                const float4 e1 = *(const float4*)&eb[d*RR + 4];
                nc[0] += xv*e0.x; nc[1] += xv*e0.y; nc[2] += xv*e0.z; nc[3] += xv*e0.w;
                nc[4] += xv*e1.x; nc[5] += xv*e1.y; nc[6] += xv*e1.z; nc[7] += xv*e1.w;
            }
        }
        if (q != 0) {
            #pragma unroll
            for (int r = 0; r < 8; ++r) pn[((q-1)*8 + r)*64 + c] = nc[r];
        }
        __syncthreads();
        // ---- reduce + coef update (one wave, c = tid) ----
        if (tid < 64) {
            float num[8], cold[8];
            #pragma unroll
            for (int r = 0; r < 8; ++r)
                num[r] = nc[r] + pn[r*64 + tid] + pn[(8+r)*64 + tid] + pn[(16+r)*64 + tid];
            if (FIRST) {
                float m = num[0];
                #pragma unroll
                for (int r = 1; r < 8; ++r) m = fmaxf(m, num[r]);
                float ssum = 0.f;
                #pragma unroll
                for (int r = 0; r < 8; ++r) { cold[r] = expf(num[r] - m); ssum += cold[r]; }
                const float inv = 1.f / ssum;
                #pragma unroll
                for (int r = 0; r < 8; ++r) cold[r] *= inv;
            } else {
                const float4 u0 = *(const float4*)&coef[(b*NNX + n0 + tid)*RR];
                const float4 u1 = *(const float4*)&coef[(b*NNX + n0 + tid)*RR + 4];
                cold[0]=u0.x; cold[1]=u0.y; cold[2]=u0.z; cold[3]=u0.w;
                cold[4]=u1.x; cold[5]=u1.y; cold[6]=u1.z; cold[7]=u1.w;
            }
            float cn[8];
            #pragma unroll
            for (int r = 0; r < 8; ++r) {
                float den = 0.f;
                #pragma unroll
                for (int s = 0; s < 8; ++s) den += cold[s] * ebteb[s*8 + r];
                cn[r] = cold[r] * num[r] / (den + EPSN);
            }
            *(float4*)&coef[(b*NNX + n0 + tid)*RR]     = make_float4(cn[0],cn[1],cn[2],cn[3]);
            *(float4*)&coef[(b*NNX + n0 + tid)*RR + 4] = make_float4(cn[4],cn[5],cn[6],cn[7]);
            #pragma unroll
            for (int r = 0; r < 8; ++r) pn[tid*8 + r] = cn[r];   // cnew [n][r] (aliases pn; single wave, read-before-write order is safe)
        }
        __syncthreads();
        // ---- ctc partial (wave 3) ----
        if (tid >= 192) {
            const int r = (tid >> 3) & 7, s = tid & 7;
            #pragma unroll 4
            for (int i = 0; i < 64; ++i) {
                const int c2 = (i + tid) & 63;
                ctcp += pn[c2*8 + r] * pn[c2*8 + s];
            }
        }
        // ---- phase 2: xc partial (threads < 160, d = tid) ----
        if (tid < DD) {
            #pragma unroll 4
            for (int n = 0; n < 64; ++n) {
                const float xv = xt[n*161 + tid];
                const float4 c0v = *(const float4*)&pn[n*8];
                const float4 c1v = *(const float4*)&pn[n*8 + 4];
                xcp[0] += xv*c0v.x; xcp[1] += xv*c0v.y; xcp[2] += xv*c0v.z; xcp[3] += xv*c0v.w;
                xcp[4] += xv*c1v.x; xcp[5] += xv*c1v.y; xcp[6] += xv*c1v.z; xcp[7] += xv*c1v.w;
            }
        }
        __syncthreads();
    }
    if (tid < DD) {
        #pragma unroll
        for (int r = 0; r < 8; ++r) atomicAdd(&xc[b*DD*RR + tid*RR + r], xcp[r]);
    }
    if (tid >= 192) {
        const int r = (tid >> 3) & 7, s = tid & 7;
        atomicAdd(&ctc[b*64 + r*8 + s], ctcp);
    }
}

// ---------------------------------------------------------------------------
// Bases multiplicative update.  tmp = Eb_old*ctc (== E(bases*ctc) algebraically).
// grid (3, 64): blockIdx.x = k-chunk, blockIdx.y = (b,r). 256 threads.
__global__ __launch_bounds__(256) void k_bupd(const float* __restrict__ E,
                                              const float* __restrict__ Eb_old,
                                              const float* __restrict__ bases_old,
                                              const float* __restrict__ xc,
                                              const float* __restrict__ ctc,
                                              float* __restrict__ bases_new) {
    __shared__ float xcl[DD];
    __shared__ float tmp[DD];
    __shared__ float ctcc[8];
    const int tid = threadIdx.x;
    const int b = blockIdx.y >> 3;
    const int r = blockIdx.y & 7;
    if (tid < 8)  ctcc[tid] = ctc[b*64 + tid*8 + r];
    if (tid < DD) xcl[tid] = xc[b*DD*RR + tid*RR + r];
    __syncthreads();
    if (tid < DD) {
        float a = 0.f;
        #pragma unroll
        for (int s = 0; s < 8; ++s) a += Eb_old[b*DD*RR + tid*RR + s] * ctcc[s];
        tmp[tid] = a;
    }
    __syncthreads();
    const int k = blockIdx.x*256 + tid;
    if (k < KKE) {
        float nb = 0.f, db = 0.f;
        #pragma unroll 4
        for (int d = 0; d < DD; ++d) {
            const float e = E[d*KKE + k];
            nb += e * xcl[d];
            db += e * tmp[d];
        }
        const float bo = bases_old[(b*KKE + k)*RR + r];
        bases_new[(b*KKE + k)*RR + r] = bo * nb / (db + EPSN);
    }
}

// ---------------------------------------------------------------------------
// Final compute_coef + reconstruction. grid (64, 8), 256 threads, 2 cols/thread.
__global__ __launch_bounds__(256) void k_final(const float* __restrict__ x,
                                               const float* __restrict__ Eb_g,
                                               const float* __restrict__ coef,
                                               float* __restrict__ out) {
    __shared__ float eb[DD*RR];
    __shared__ float ebteb[64];
    const int tid = threadIdx.x;
    const int b = blockIdx.y;
    const int n0 = blockIdx.x*512 + tid*2;

    for (int i = tid; i < DD*RR; i += 256) eb[i] = Eb_g[b*DD*RR + i];
    __syncthreads();
    if (tid < 64) {
        const int r = tid >> 3, s = tid & 7;
        float a = 0.f;
        #pragma unroll 4
        for (int d = 0; d < DD; ++d) a += eb[d*RR + r] * eb[d*RR + s];
        ebteb[tid] = a;
    }
    __syncthreads();

    float a0[8] = {0,0,0,0,0,0,0,0};
    float a1[8] = {0,0,0,0,0,0,0,0};
    #pragma unroll 4
    for (int d = 0; d < DD; ++d) {
        const float2 xv = *(const float2*)&x[(b*DD + d)*NNX + n0];
        const float4 e0 = *(const float4*)&eb[d*RR];
        const float4 e1 = *(const float4*)&eb[d*RR + 4];
        a0[0] += xv.x*e0.x; a0[1] += xv.x*e0.y; a0[2] += xv.x*e0.z; a0[3] += xv.x*e0.w;
        a0[4] += xv.x*e1.x; a0[5] += xv.x*e1.y; a0[6] += xv.x*e1.z; a0[7] += xv.x*e1.w;
        a1[0] += xv.y*e0.x; a1[1] += xv.y*e0.y; a1[2] += xv.y*e0.z; a1[3] += xv.y*e0.w;
        a1[4] += xv.y*e1.x; a1[5] += xv.y*e1.y; a1[6] += xv.y*e1.z; a1[7] += xv.y*e1.w;
    }
    const float* cp = &coef[(b*NNX + n0)*RR];
    const float4 u0 = ((const float4*)cp)[0];
    const float4 u1 = ((const float4*)cp)[1];
    const float4 u2 = ((const float4*)cp)[2];
    const float4 u3 = ((const float4*)cp)[3];
    const float c0a[8] = {u0.x,u0.y,u0.z,u0.w,u1.x,u1.y,u1.z,u1.w};
    const float c1a[8] = {u2.x,u2.y,u2.z,u2.w,u3.x,u3.y,u3.z,u3.w};
    float cf0[8], cf1[8];
    #pragma unroll
    for (int r = 0; r < 8; ++r) {
        float d0 = 0.f, d1 = 0.f;
        #pragma unroll
        for (int s = 0; s < 8; ++s) {
            const float t = ebteb[s*8 + r];
            d0 += c0a[s]*t; d1 += c1a[s]*t;
        }
        cf0[r] = c0a[r]*a0[r]/(d0 + EPSN);
        cf1[r] = c1a[r]*a1[r]/(d1 + EPSN);
    }
    #pragma unroll 4
    for (int d = 0; d < DD; ++d) {
        const float4 e0 = *(const float4*)&eb[d*RR];
        const float4 e1 = *(const float4*)&eb[d*RR + 4];
        float o0 = e0.x*cf0[0] + e0.y*cf0[1] + e0.z*cf0[2] + e0.w*cf0[3]
                 + e1.x*cf0[4] + e1.y*cf0[5] + e1.z*cf0[6] + e1.w*cf0[7];
        float o1 = e0.x*cf1[0] + e0.y*cf1[1] + e0.z*cf1[2] + e0.w*cf1[3]
                 + e1.x*cf1[4] + e1.y*cf1[5] + e1.z*cf1[6] + e1.w*cf1[7];
        *(float2*)&out[(b*DD + d)*NNX + n0] = make_float2(o0, o1);
    }
}

// ---------------------------------------------------------------------------
extern "C" void kernel_launch(void* const* d_in, const int* in_sizes, int n_in,
                              void* d_out, int out_size, void* d_ws, size_t ws_size,
                              hipStream_t stream) {
    const float* x     = (const float*)d_in[0];
    const float* binit = (const float*)d_in[1];
    float* out = (float*)d_out;

    float* w      = (float*)d_ws;
    float* E      = w;                       // 94240
    float* ET     = E      + DD*KKE;         // 94240
    float* bases0 = ET     + DD*KKE;         // 37696
    float* bases1 = bases0 + NB*KKE*RR;      // 37696
    float* Eb0    = bases1 + NB*KKE*RR;      // 10240
    float* Eb1    = Eb0    + NB*DD*RR;       // 10240
    float* coef   = Eb1    + NB*DD*RR;       // 2097152
    float* xc     = coef   + (size_t)NB*NNX*RR; // 10240
    float* ctc    = xc     + NB*DD*RR;       // 512

    const dim3 gstep(128, 8), gbupd(3, 64), gfin(64, 8);

    k_build<<<160, 256, 0, stream>>>(E, ET);
    k_eb<true><<<64, 256, 0, stream>>>(ET, binit, bases0, Eb0, xc, ctc);

    // step 1 (fused with softmax init)
    k_step<true><<<gstep, 256, 0, stream>>>(x, Eb0, coef, xc, ctc);
    k_bupd<<<gbupd, 256, 0, stream>>>(E, Eb0, bases0, xc, ctc, bases1);
    k_eb<false><<<64, 256, 0, stream>>>(ET, bases1, bases1, Eb1, xc, ctc);
    // step 2
    k_step<false><<<gstep, 256, 0, stream>>>(x, Eb1, coef, xc, ctc);
    k_bupd<<<gbupd, 256, 0, stream>>>(E, Eb1, bases1, xc, ctc, bases0);
    k_eb<false><<<64, 256, 0, stream>>>(ET, bases0, bases0, Eb0, xc, ctc);
    // step 3
    k_step<false><<<gstep, 256, 0, stream>>>(x, Eb0, coef, xc, ctc);
    k_bupd<<<gbupd, 256, 0, stream>>>(E, Eb0, bases0, xc, ctc, bases1);
    k_eb<false><<<64, 256, 0, stream>>>(ET, bases1, bases1, Eb1, xc, ctc);
    // step 4
    k_step<false><<<gstep, 256, 0, stream>>>(x, Eb1, coef, xc, ctc);
    k_bupd<<<gbupd, 256, 0, stream>>>(E, Eb1, bases1, xc, ctc, bases0);
    k_eb<false><<<64, 256, 0, stream>>>(ET, bases0, bases0, Eb0, xc, ctc);
    // compute_coef + reconstruction
    k_final<<<gfin, 256, 0, stream>>>(x, Eb0, coef, out);
}